// Round 2
// 238.683 us; speedup vs baseline: 1.0085x; 1.0085x over previous
//
#include <hip/hip_runtime.h>
#include <math.h>

#define BLK 256

// Address-space types for the global->LDS DMA builtin.
typedef __attribute__((address_space(1))) void gvoid_t;
typedef __attribute__((address_space(3))) void lvoid_t;

// HW-verified widths ONLY: 16B (m97) and 4B (m03). LDS dest = wave-uniform
// base + lane*width. width=12 is NOT verified and scrambled data in R1.
__device__ __forceinline__ void lds_dma16(const float* gsrc, float* ldst) {
    __builtin_amdgcn_global_load_lds((gvoid_t*)gsrc, (lvoid_t*)ldst, 16, 0, 0);
}
__device__ __forceinline__ void lds_dma4(const float* gsrc, float* ldst) {
    __builtin_amdgcn_global_load_lds((gvoid_t*)gsrc, (lvoid_t*)ldst, 4, 0, 0);
}

// 12-byte, 4-aligned POD so the compiler emits a single dwordx3 per-lane load.
struct F3 { float x, y, z; };

__global__ __launch_bounds__(BLK, 8) void wasserstein_kernel(
    const float* __restrict__ loc1,   const float* __restrict__ scale1,
    const float* __restrict__ rot1,   const float* __restrict__ loc2,
    const float* __restrict__ scale2, const float* __restrict__ rot2,
    float* __restrict__ out)
{
    // Per-wave PRIVATE rot slabs (no cross-wave sharing -> no __syncthreads).
    // 2 rots * 576 floats per wave * 4 waves = 4608 floats = 18432 B
    //  -> 8 blocks/CU (147456 B of 160 KiB), 32 waves/CU = 100% occupancy.
    // Slab layout is LINEAR (forced by global_load_lds: base + lane*width):
    //   issue0 w16: floats   0..255  at slab + lane*16B
    //   issue1 w16: floats 256..511  at slab + 1024B + lane*16B
    //   issue2 w4 : floats 512..575  at slab + 2048B + lane*4B
    __shared__ __align__(16) float smem[4 * 1152];

    const int tid  = threadIdx.x;
    const int lane = tid & 63;
    const int wave = tid >> 6;
    const long long blockStart = (long long)blockIdx.x * BLK;
    const long long waveStart  = blockStart + (long long)(wave * 64);

    float* wR1 = smem + wave * 1152;   // 576 floats: this wave's rot1 rows
    float* wR2 = wR1 + 576;            // 576 floats: this wave's rot2 rows

    // ---- async DMA: 6 issues per wave, all in flight until one vmcnt wait ----
    {
        const float* g1 = rot1 + waveStart * 9;   // 2304 B, 16B-aligned
        const float* g2 = rot2 + waveStart * 9;
        lds_dma16(g1 + lane * 4,       wR1);
        lds_dma16(g1 + 256 + lane * 4, wR1 + 256);
        lds_dma4 (g1 + 512 + lane,     wR1 + 512);
        lds_dma16(g2 + lane * 4,       wR2);
        lds_dma16(g2 + 256 + lane * 4, wR2 + 256);
        lds_dma4 (g2 + 512 + lane,     wR2 + 512);
    }

    // ---- direct per-thread loc/scale loads (12 B each, wave-contiguous) ----
    const long long i = blockStart + tid;
    const F3 L1 = *reinterpret_cast<const F3*>(loc1   + i * 3);
    const F3 L2 = *reinterpret_cast<const F3*>(loc2   + i * 3);
    const F3 S1 = *reinterpret_cast<const F3*>(scale1 + i * 3);
    const F3 S2 = *reinterpret_cast<const F3*>(scale2 + i * 3);

    const float dx = L1.x - L2.x, dy = L1.y - L2.y, dz = L1.z - L2.z;
    const float loc_diff2 = dx * dx + dy * dy + dz * dz;
    const float s1a = S1.x, s1b = S1.y, s1c = S1.z;
    const float s2a = S2.x, s2b = S2.y, s2c = S2.z;

    // Wait for this wave's DMA (vmcnt covers global_load_lds), then fence the
    // scheduler so LDS reads cannot be hoisted above the wait.
    asm volatile("s_waitcnt vmcnt(0)" ::: "memory");
    __builtin_amdgcn_sched_barrier(0);

    float R1[9], R2[9];
#pragma unroll
    for (int k = 0; k < 9; ++k) R1[k] = wR1[lane * 9 + k];
#pragma unroll
    for (int k = 0; k < 9; ++k) R2[k] = wR2[lane * 9 + k];

    // M2 = R2 diag(s2) R2^T  (symmetric; 6 unique entries)
    const float m00 = s2a * R2[0] * R2[0] + s2b * R2[1] * R2[1] + s2c * R2[2] * R2[2];
    const float m01 = s2a * R2[0] * R2[3] + s2b * R2[1] * R2[4] + s2c * R2[2] * R2[5];
    const float m02 = s2a * R2[0] * R2[6] + s2b * R2[1] * R2[7] + s2c * R2[2] * R2[8];
    const float m11 = s2a * R2[3] * R2[3] + s2b * R2[4] * R2[4] + s2c * R2[5] * R2[5];
    const float m12 = s2a * R2[3] * R2[6] + s2b * R2[4] * R2[7] + s2c * R2[5] * R2[8];
    const float m22 = s2a * R2[6] * R2[6] + s2b * R2[7] * R2[7] + s2c * R2[8] * R2[8];

    // A = M2 * R1
    float A[9];
    A[0] = m00 * R1[0] + m01 * R1[3] + m02 * R1[6];
    A[1] = m00 * R1[1] + m01 * R1[4] + m02 * R1[7];
    A[2] = m00 * R1[2] + m01 * R1[5] + m02 * R1[8];
    A[3] = m01 * R1[0] + m11 * R1[3] + m12 * R1[6];
    A[4] = m01 * R1[1] + m11 * R1[4] + m12 * R1[7];
    A[5] = m01 * R1[2] + m11 * R1[5] + m12 * R1[8];
    A[6] = m02 * R1[0] + m12 * R1[3] + m22 * R1[6];
    A[7] = m02 * R1[1] + m12 * R1[4] + m22 * R1[7];
    A[8] = m02 * R1[2] + m12 * R1[5] + m22 * R1[8];

    // T = R1^T * A
    float T[9];
    T[0] = R1[0] * A[0] + R1[3] * A[3] + R1[6] * A[6];
    T[1] = R1[0] * A[1] + R1[3] * A[4] + R1[6] * A[7];
    T[2] = R1[0] * A[2] + R1[3] * A[5] + R1[6] * A[8];
    T[3] = R1[1] * A[0] + R1[4] * A[3] + R1[7] * A[6];
    T[4] = R1[1] * A[1] + R1[4] * A[4] + R1[7] * A[7];
    T[5] = R1[1] * A[2] + R1[4] * A[5] + R1[7] * A[8];
    T[6] = R1[2] * A[0] + R1[5] * A[3] + R1[8] * A[6];
    T[7] = R1[2] * A[1] + R1[5] * A[4] + R1[8] * A[7];
    T[8] = R1[2] * A[2] + R1[5] * A[5] + R1[8] * A[8];

    // E = diag(sqrt(s1)) T diag(sqrt(s1)), symmetrized
    const float sq0 = sqrtf(s1a), sq1 = sqrtf(s1b), sq2 = sqrtf(s1c);
    const float e00 = s1a * T[0];
    const float e11 = s1b * T[4];
    const float e22 = s1c * T[8];
    const float e01 = 0.5f * sq0 * sq1 * (T[1] + T[3]);
    const float e02 = 0.5f * sq0 * sq2 * (T[2] + T[6]);
    const float e12 = 0.5f * sq1 * sq2 * (T[5] + T[7]);

    // Analytic eigenvalues of symmetric 3x3 (trigonometric / Smith's method)
    const float q  = (e00 + e11 + e22) * (1.0f / 3.0f);
    const float p1 = e01 * e01 + e02 * e02 + e12 * e12;
    const float d0 = e00 - q, d1 = e11 - q, d2 = e22 - q;
    const float p2 = d0 * d0 + d1 * d1 + d2 * d2 + 2.0f * p1;

    float trace_sqrt;
    if (p2 > 1e-24f) {
        const float p   = sqrtf(p2 * (1.0f / 6.0f));
        const float inv = 1.0f / p;
        const float b00 = d0 * inv, b11 = d1 * inv, b22 = d2 * inv;
        const float b01 = e01 * inv, b02 = e02 * inv, b12 = e12 * inv;
        float detB = b00 * (b11 * b22 - b12 * b12)
                   - b01 * (b01 * b22 - b12 * b02)
                   + b02 * (b01 * b12 - b11 * b02);
        float r = 0.5f * detB;
        r = fminf(fmaxf(r, -1.0f), 1.0f);
        const float phi  = acosf(r) * (1.0f / 3.0f);
        const float twop = 2.0f * p;
        const float eig1 = q + twop * cosf(phi);
        const float eig3 = q + twop * cosf(phi + 2.0943951023931953f); // + 2*pi/3
        const float eig2 = 3.0f * q - eig1 - eig3;
        trace_sqrt = sqrtf(fabsf(eig1)) + sqrtf(fabsf(eig2)) + sqrtf(fabsf(eig3));
    } else {
        trace_sqrt = 3.0f * sqrtf(fabsf(q));
    }

    float cov_w = (s1a + s1b + s1c) + (s2a + s2b + s2c) - 2.0f * trace_sqrt;
    cov_w = fmaxf(cov_w, 0.0f);
    out[i] = sqrtf(loc_diff2 + cov_w);
}

extern "C" void kernel_launch(void* const* d_in, const int* in_sizes, int n_in,
                              void* d_out, int out_size, void* d_ws, size_t ws_size,
                              hipStream_t stream) {
    const float* loc1   = (const float*)d_in[0];
    const float* scale1 = (const float*)d_in[1];
    const float* rot1   = (const float*)d_in[2];
    const float* loc2   = (const float*)d_in[3];
    const float* scale2 = (const float*)d_in[4];
    const float* rot2   = (const float*)d_in[5];
    float* out = (float*)d_out;

    const int B = in_sizes[0] / 3;   // 2097152; divisible by BLK
    const int grid = B / BLK;

    wasserstein_kernel<<<grid, BLK, 0, stream>>>(loc1, scale1, rot1,
                                                 loc2, scale2, rot2, out);
}